// Round 14
// baseline (275.248 us; speedup 1.0000x reference)
//
#include <hip/hip_runtime.h>
#include <cstdint>

#define SEQ 4096
#define NH 12
#define DH 64
#define DM 768
#define MT 8192      // B*SEQ
#define QKVN 2304    // 3*DM
#define BH 24        // B*NH

typedef __bf16 bf16;
typedef __attribute__((ext_vector_type(8))) __bf16 bf16x8;
typedef __attribute__((ext_vector_type(4))) __bf16 bf16x4;
typedef __attribute__((ext_vector_type(2))) __bf16 bf16x2;
typedef __attribute__((ext_vector_type(4))) float f32x4;
typedef __attribute__((ext_vector_type(16))) float f32x16;
typedef __attribute__((ext_vector_type(2))) int int2v;

// async global->LDS, 16B per lane. LDS dest is wave-uniform base + lane*16.
__device__ __forceinline__ void async_ld16(const void* g, void* lds) {
  __builtin_amdgcn_global_load_lds(
      (__attribute__((address_space(1))) void*)(void*)g,
      (__attribute__((address_space(3))) void*)lds, 16, 0, 0);
}

// Schraudolph exp2 in the f32-bit domain: bits = (int)(s*2^23 + 16252*65536).
// bits>>16 are the bf16(2^s) bits; bits&0xffff0000 reinterpreted as f32 is
// EXACTLY the bf16 P value — so the VALU rowsum matches PV's P bit-for-bit.
__device__ __forceinline__ int sexp2_bits(float s) {
  return (int)__builtin_fmaf(s, 8388608.0f, 1065091072.0f);
}

// pack {lo.hi16, hi.hi16} -> one dword (two bf16 lanes)
__device__ __forceinline__ int pack_hi16(int lo, int hi) {
#if __has_builtin(__builtin_amdgcn_perm)
  return (int)__builtin_amdgcn_perm((unsigned)hi, (unsigned)lo, 0x07060302u);
#else
  return (int)(((unsigned)lo >> 16) | ((unsigned)hi & 0xffff0000u));
#endif
}

// (a,b) -> a' = {a.lo32, b.lo32}, b' = {a.hi32, b.hi32}
__device__ __forceinline__ void lane32_swap(int& a, int& b) {
#if __has_builtin(__builtin_amdgcn_permlane32_swap)
  int2v r = __builtin_amdgcn_permlane32_swap(a, b, false, false);
  a = r.x; b = r.y;
#else
  int hi = (threadIdx.x & 63) >> 5;
  int ra = __shfl_xor(a, 32, 64), rb = __shfl_xor(b, 32, 64);
  int na = hi ? rb : a;
  int nb = hi ? b : ra;
  a = na; b = nb;
#endif
}

// ---------------------------------------------------------------- converts (merged)
#define NX4  (MT * DM / 4)
#define NW14 (QKVN * DM / 4)
#define NW24 (DM * DM / 4)
__global__ void cvt_all(const float* __restrict__ x, const float* __restrict__ w1,
                        const float* __restrict__ w2, bf16* __restrict__ xb,
                        bf16* __restrict__ wb1, bf16* __restrict__ wb2) {
  int i = blockIdx.x * blockDim.x + threadIdx.x;
  const float* src; bf16* dst; int j;
  if (i < NX4) { src = x; dst = xb; j = i; }
  else if (i < NX4 + NW14) { src = w1; dst = wb1; j = i - NX4; }
  else if (i < NX4 + NW14 + NW24) { src = w2; dst = wb2; j = i - NX4 - NW14; }
  else return;
  f32x4 v = ((const f32x4*)src)[j];
  bf16x4 o;
  o.x = (bf16)v.x; o.y = (bf16)v.y; o.z = (bf16)v.z; o.w = (bf16)v.w;
  ((bf16x4*)dst)[j] = o;
}

// ---------------------------------------------------------------- GEMM (B^T)
// C[M,N] = A[M,K] @ Bw[N,K]^T. 128x128 tile, BK=64, 4 waves, 64x64/wave.
// Global-side XOR granule swizzle; fragment reads g = G ^ (row&7), conflict-free.
// R28: Q/K epilogue now bounces through LDS (sT2 [128][72] bf16, aliases sA/sB
// after the final K-loop barrier — same trick the V path already used) and
// stores bf16x8 fully coalesced (1KB/wave-inst), replacing 64 scattered 2B
// stores per thread.
// MODE 0: QKV epilogue -> +bias, Q(*0.125*log2e)/K as [bh][n][d]; V^T -> [bh][d][n]
// MODE 1: out-proj epilogue -> +bias, fp32 row-major [M,N] (fallback path only)
template<int MODE>
__global__ __launch_bounds__(256) void gemm_bt(
    const bf16* __restrict__ A, const bf16* __restrict__ Bw,
    const float* __restrict__ bias,
    bf16* __restrict__ outQ, bf16* __restrict__ outK, bf16* __restrict__ outVt,
    float* __restrict__ outF,
    int M, int N, int K)
{
  __shared__ bf16 smem[2 * 128 * 64];   // sA | sB ; sT aliases the front
  bf16* sA = smem;
  bf16* sB = smem + 128 * 64;
  bf16* sT = smem;                      // reused only after the final K-loop barrier

  const int tid  = threadIdx.x;
  const int wave = tid >> 6;
  const int lane = tid & 63;
  const int l15  = lane & 15;
  const int quad = lane >> 4;

  constexpr int NT = (MODE == 0) ? (QKVN / 128) : (DM / 128);
  const int lin = blockIdx.x;
  const int rem = lin % (NT * 8);
  const int m0 = ((lin / (NT * 8)) * 8 + (rem % 8)) * 128;
  const int n0 = (rem / 8) * 128;

  const int rowbase = (wave >> 1) * 64;
  const int colbase = (wave & 1) * 64;

  f32x4 acc[4][4] = {};

  const int srow = lane >> 3;            // row within 8-row chunk
  const int spg  = (lane & 7) ^ srow;    // swizzled 16B granule within 128B row
  const int xk   = l15 & 7;              // fragment-read swizzle key

  for (int kt = 0; kt < K; kt += 64) {
#pragma unroll
    for (int p = 0; p < 8; ++p) {
      int chunk = p * 4 + wave;
      if (chunk < 16) {
        int row = chunk * 8 + srow;
        async_ld16(A + (size_t)(m0 + row) * K + kt + spg * 8, &sA[chunk * 512]);
      } else {
        int row = (chunk - 16) * 8 + srow;
        async_ld16(Bw + (size_t)(n0 + row) * K + kt + spg * 8, &sB[(chunk - 16) * 512]);
      }
    }
    __syncthreads();

#pragma unroll
    for (int ks = 0; ks < 2; ++ks) {
      bf16x8 af[4], bfr[4];
#pragma unroll
      for (int rt = 0; rt < 4; ++rt)
        af[rt] = *(const bf16x8*)&sA[(rowbase + rt * 16 + l15) * 64 +
                                     (((ks * 4 + quad) ^ xk) * 8)];
#pragma unroll
      for (int ct = 0; ct < 4; ++ct)
        bfr[ct] = *(const bf16x8*)&sB[(colbase + ct * 16 + l15) * 64 +
                                      (((ks * 4 + quad) ^ xk) * 8)];
#pragma unroll
      for (int rt = 0; rt < 4; ++rt)
#pragma unroll
        for (int ct = 0; ct < 4; ++ct)
          acc[rt][ct] = __builtin_amdgcn_mfma_f32_16x16x32_bf16(af[rt], bfr[ct], acc[rt][ct], 0, 0, 0);
    }
    __syncthreads();
  }

  if (MODE == 0) {
    const int g = n0 / DM;                       // uniform per block (0=q,1=k,2=v)
    if (g < 2) {
      // Q/K: LDS bounce sT[m][72] -> coalesced bf16x8 stores along d
      const float sc = (g == 0) ? 0.125f * 1.4426950408889634f : 1.0f;
      bf16* outQK = (g == 0) ? outQ : outK;
      const int f0q = n0 - g * DM;               // offset within the 768-wide group
      const int b = m0 >> 12, n0m = m0 & 4095;   // tile lies within one batch
#pragma unroll
      for (int p = 0; p < 2; ++p) {
        __syncthreads();
        if (colbase == p * 64) {
#pragma unroll
          for (int ct = 0; ct < 4; ++ct) {
            int c = ct * 16 + l15;
            float bj = bias[n0 + p * 64 + c];
#pragma unroll
            for (int rt = 0; rt < 4; ++rt) {
              int ml = rowbase + rt * 16 + quad * 4;
#pragma unroll
              for (int r = 0; r < 4; ++r)
                sT[(ml + r) * 72 + c] = (bf16)((acc[rt][ct][r] + bj) * sc);
            }
          }
        }
        __syncthreads();
        const int h = (f0q + p * 64) >> 6;
        const int bh = b * NH + h;
#pragma unroll
        for (int p2 = 0; p2 < 4; ++p2) {
          int slot = p2 * 256 + tid;
          int mr = slot >> 3, cg = slot & 7;
          *(bf16x8*)&outQK[((size_t)bh * SEQ + n0m + mr) * DH + cg * 8] =
              *(const bf16x8*)&sT[mr * 72 + cg * 8];
        }
      }
    } else {
      // V block: bounce through LDS, store V^T coalesced along n
      const int f0 = n0 - 2 * DM;
      const int b = m0 >> 12, n0m = m0 & 4095;
#pragma unroll
      for (int p = 0; p < 2; ++p) {
        __syncthreads();
        if (colbase == p * 64) {
#pragma unroll
          for (int ct = 0; ct < 4; ++ct) {
            int jl = ct * 16 + l15;
            float bj = bias[n0 + p * 64 + jl];
#pragma unroll
            for (int rt = 0; rt < 4; ++rt) {
              int ml = rowbase + rt * 16 + quad * 4;
#pragma unroll
              for (int r = 0; r < 4; ++r)
                sT[jl * 136 + ml + r] = (bf16)(acc[rt][ct][r] + bj);
            }
          }
        }
        __syncthreads();
#pragma unroll
        for (int p2 = 0; p2 < 4; ++p2) {
          int slot = p2 * 256 + tid;
          int jr = slot >> 4, mc = (slot & 15) * 8;
          int fj = f0 + p * 64 + jr;
          int h = fj >> 6, d = fj & 63;
          *(bf16x8*)&outVt[((size_t)(b * NH + h) * DH + d) * SEQ + n0m + mc] =
              *(const bf16x8*)&sT[jr * 136 + mc];
        }
      }
    }
  } else {
#pragma unroll
    for (int ct = 0; ct < 4; ++ct) {
      int j = n0 + colbase + ct * 16 + l15;
      float bj = bias[j];
#pragma unroll
      for (int rt = 0; rt < 4; ++rt) {
        int mrow = m0 + rowbase + rt * 16 + quad * 4;
#pragma unroll
        for (int r = 0; r < 4; ++r)
          outF[(size_t)(mrow + r) * N + j] = acc[rt][ct][r] + bj;
      }
    }
  }
}

// ---------------------------------------------------------------- out-proj GEMM with fused split-K merge
// R28 (resubmitted R29 after broker timeout): merge_halves folded into the
// out-proj GEMM's A-staging. BK=64 == one head per K-step, so the A-tile rows
// map to one (bh, q) range of the Op partials. Per K-step each thread
// reg-loads 8 f32 from each key-half, computes (O0+O1)/(r0+r1) (exactly
// merge_halves' math -> absmax unchanged), converts to bf16 and ds_writes to
// the XOR-swizzled granule the fragment reads expect: LDS granule
// (gd ^ (row&7)) holds K-granule gd.
// Removes one kernel + the 37MB attnV write / ~150MB re-read.
__global__ __launch_bounds__(256) void gemm_out_fused(
    const float* __restrict__ Op, const float* __restrict__ Rs,
    const bf16* __restrict__ Bw, const float* __restrict__ bias,
    float* __restrict__ outF)
{
  __shared__ bf16 smem[2 * 128 * 64];
  bf16* sA = smem;
  bf16* sB = smem + 128 * 64;

  const int tid  = threadIdx.x;
  const int wave = tid >> 6;
  const int lane = tid & 63;
  const int l15  = lane & 15;
  const int quad = lane >> 4;

  const int lin = blockIdx.x;
  const int rem = lin % 48;                      // NT*8, NT = DM/128 = 6
  const int m0 = ((lin / 48) * 8 + (rem % 8)) * 128;
  const int n0 = (rem / 8) * 128;

  const int rowbase = (wave >> 1) * 64;
  const int colbase = (wave & 1) * 64;

  f32x4 acc[4][4] = {};

  const int srow = lane >> 3;
  const int spg  = (lane & 7) ^ srow;
  const int xk   = l15 & 7;
  const int arow = wave * 8 + (lane >> 3);       // A-merge row within 32-row slice
  const int gd   = lane & 7;                     // A-merge K-granule (8 bf16)

  for (int kt = 0; kt < DM; kt += 64) {
    const int h = kt >> 6;                       // head for this K-step
    // B: 16 chunks of 1KB via async global->LDS (swizzled on the global side)
#pragma unroll
    for (int p = 0; p < 4; ++p) {
      int chunk = p * 4 + wave;
      int row = chunk * 8 + srow;
      async_ld16(Bw + (size_t)(n0 + row) * DM + kt + spg * 8, &sB[chunk * 512]);
    }
    // A: reg-merge the split-K partials -> bf16 -> swizzled ds_write_b128
#pragma unroll
    for (int s = 0; s < 4; ++s) {
      int row = s * 32 + arow;
      int m = m0 + row;
      int bg = m >> 12, q = m & 4095;
      size_t rbase = (size_t)(bg * NH + h) * SEQ + q;
      const float* p0 = Op + rbase * DH + gd * 8;
      const float* p1 = p0 + (size_t)BH * SEQ * DH;
      f32x4 x0 = *(const f32x4*)p0;
      f32x4 x1 = *(const f32x4*)(p0 + 4);
      f32x4 y0 = *(const f32x4*)p1;
      f32x4 y1 = *(const f32x4*)(p1 + 4);
      float inv = 1.0f / (Rs[rbase] + Rs[(size_t)BH * SEQ + rbase]);
      bf16x8 o;
#pragma unroll
      for (int j = 0; j < 4; ++j) {
        o[j]     = (bf16)((x0[j] + y0[j]) * inv);
        o[4 + j] = (bf16)((x1[j] + y1[j]) * inv);
      }
      *(bf16x8*)&sA[row * 64 + (gd ^ (row & 7)) * 8] = o;
    }
    __syncthreads();

#pragma unroll
    for (int ks = 0; ks < 2; ++ks) {
      bf16x8 af[4], bfr[4];
#pragma unroll
      for (int rt = 0; rt < 4; ++rt)
        af[rt] = *(const bf16x8*)&sA[(rowbase + rt * 16 + l15) * 64 +
                                     (((ks * 4 + quad) ^ xk) * 8)];
#pragma unroll
      for (int ct = 0; ct < 4; ++ct)
        bfr[ct] = *(const bf16x8*)&sB[(colbase + ct * 16 + l15) * 64 +
                                      (((ks * 4 + quad) ^ xk) * 8)];
#pragma unroll
      for (int rt = 0; rt < 4; ++rt)
#pragma unroll
        for (int ct = 0; ct < 4; ++ct)
          acc[rt][ct] = __builtin_amdgcn_mfma_f32_16x16x32_bf16(af[rt], bfr[ct], acc[rt][ct], 0, 0, 0);
    }
    __syncthreads();
  }

#pragma unroll
  for (int ct = 0; ct < 4; ++ct) {
    int j = n0 + colbase + ct * 16 + l15;
    float bj = bias[j];
#pragma unroll
    for (int rt = 0; rt < 4; ++rt) {
      int mrow = m0 + rowbase + rt * 16 + quad * 4;
#pragma unroll
      for (int r = 0; r < 4; ++r)
        outF[(size_t)(mrow + r) * DM + j] = acc[rt][ct][r] + bj;
    }
  }
}

// ---------------------------------------------------------------- flash attention v19
// R24 (measured round 12): 123.0 us, VGPR 128, zero spill, split-K even
// 768 blocks. Plateau note: v15 (2x LDS traffic) 127.7, R16 (-20% MFMA) 127.4,
// R24 123.0 — flash is stall-bound (~70% unaccounted cycles), not pipe-bound.
// Untouched this round.
#define SOFTPV(S, R0, R1, R2, R3, OA, OB) do {                               \
    int b0 = sexp2_bits(S[8*kc+0]); int b1 = sexp2_bits(S[8*kc+1]);          \
    int b2 = sexp2_bits(S[8*kc+2]); int b3 = sexp2_bits(S[8*kc+3]);          \
    int b4 = sexp2_bits(S[8*kc+4]); int b5 = sexp2_bits(S[8*kc+5]);          \
    int b6 = sexp2_bits(S[8*kc+6]); int b7 = sexp2_bits(S[8*kc+7]);          \
    R0 += __int_as_float(b0 & 0xffff0000) + __int_as_float(b4 & 0xffff0000); \
    R1 += __int_as_float(b1 & 0xffff0000) + __int_as_float(b5 & 0xffff0000); \
    R2 += __int_as_float(b2 & 0xffff0000) + __int_as_float(b6 & 0xffff0000); \
    R3 += __int_as_float(b3 & 0xffff0000) + __int_as_float(b7 & 0xffff0000); \
    int g0a = pack_hi16(b0, b1), g0b = pack_hi16(b2, b3);                    \
    int g1a = pack_hi16(b4, b5), g1b = pack_hi16(b6, b7);                    \
    lane32_swap(g0a, g1a); lane32_swap(g0b, g1b);                            \
    union { int i[4]; bf16x8 v; } Af_;                                       \
    Af_.i[0] = g0a; Af_.i[1] = g0b; Af_.i[2] = g1a; Af_.i[3] = g1b;          \
    OA = __builtin_amdgcn_mfma_f32_32x32x16_bf16(Af_.v, vf0, OA, 0, 0, 0);   \
    OB = __builtin_amdgcn_mfma_f32_32x32x16_bf16(Af_.v, vf1, OB, 0, 0, 0);   \
  } while (0)

template<int SPLIT>
__global__ __launch_bounds__(256, 2) void flash_attn(
    const bf16* __restrict__ Q, const bf16* __restrict__ Kg,
    const bf16* __restrict__ Vt, float* __restrict__ Op,
    float* __restrict__ Rs, bf16* __restrict__ Oout)
{
  __shared__ bf16 sK[2][64 * 64];    // [key][d], granule-swizzled
  __shared__ bf16 sV[2][64 * 64];    // [d][key], granule-swizzled

  int bh, qb, kh;
  if (SPLIT) {
    const int L    = blockIdx.x + 32 * blockIdx.y;          // 0..767
    const int slot = L >> 3;                                // 0..95
    bh = (L & 7) + 8 * (slot >> 5);
    qb = (slot & 31) >> 1;
    kh = slot & 1;
  } else {
    const int L    = blockIdx.x + 16 * blockIdx.y;          // 0..383
    const int slot = L >> 3;                                // 0..47
    bh = (L & 7) + 8 * (slot >> 4);
    qb = slot & 15;
    kh = 0;
  }

  {
    int ph = (qb + bh + kh) & 3;
    if (ph == 1) __builtin_amdgcn_s_sleep(2);
    else if (ph == 2) __builtin_amdgcn_s_sleep(4);
    else if (ph == 3) __builtin_amdgcn_s_sleep(6);
  }

  const int tid  = threadIdx.x;
  const int wave = tid >> 6;
  const int lane = tid & 63;
  const int l31  = lane & 31;
  const int hi   = lane >> 5;
  const int q0w  = qb * 256 + wave * 64;    // 64 q-rows per wave (two 32-row sets)
  const int kbase = SPLIT ? kh * (SEQ / 2) : 0;
  const int kend  = SPLIT ? kbase + SEQ / 2 : SEQ;

  const bf16* Qb = Q  + (size_t)bh * SEQ * DH;
  const bf16* Kb = Kg + (size_t)bh * SEQ * DH;
  const bf16* Vb = Vt + (size_t)bh * DH * SEQ;

  const int srow = lane >> 3;
  const int spg  = lane & 7;

  bf16x8 qf0[4], qf1[4];
#pragma unroll
  for (int dc = 0; dc < 4; ++dc) {
    qf0[dc] = *(const bf16x8*)&Qb[(size_t)(q0w + l31) * DH + dc * 16 + hi * 8];
    qf1[dc] = *(const bf16x8*)&Qb[(size_t)(q0w + 32 + l31) * DH + dc * 16 + hi * 8];
  }

  f32x16 o00 = {}, o01 = {}, o10 = {}, o11 = {};
  const f32x16 zc = {};
  float r00 = 0.f, r01 = 0.f, r02 = 0.f, r03 = 0.f;
  float r10 = 0.f, r11 = 0.f, r12 = 0.f, r13 = 0.f;

  const int keyk = (l31 & 7) ^ (((l31 >> 3) & 3) << 1);
  int off[4];                       // shared K/V fragment offsets (identical maps)
#pragma unroll
  for (int dc = 0; dc < 4; ++dc)
    off[dc] = l31 * 64 + (((dc * 2 + hi) ^ keyk) * 8);

  auto stage = [&](int kt, int buf) {
#pragma unroll
    for (int j = 0; j < 2; ++j) {
      int r0 = wave * 16 + j * 8;
      int row = r0 + srow;
      int lg = spg ^ (row & 7) ^ (((row >> 3) & 3) << 1);
      async_ld16(Kb + (size_t)(kt + row) * DH + lg * 8, &sK[buf][r0 * 64]);
      async_ld16(Vb + (size_t)row * SEQ + kt + lg * 8, &sV[buf][r0 * 64]);
    }
  };

  auto compute = [&](const bf16* sKp, const bf16* sVp) {
#pragma unroll
    for (int kb = 0; kb < 2; ++kb) {
      bf16x8 kf[4];
#pragma unroll
      for (int dc = 0; dc < 4; ++dc)
        kf[dc] = *(const bf16x8*)&sKp[off[dc] + kb * 2048];
      f32x16 s0 = __builtin_amdgcn_mfma_f32_32x32x16_bf16(kf[0], qf0[0], zc, 0, 0, 0);
      f32x16 s1 = __builtin_amdgcn_mfma_f32_32x32x16_bf16(kf[0], qf1[0], zc, 0, 0, 0);
#pragma unroll
      for (int dc = 1; dc < 4; ++dc) {
        s0 = __builtin_amdgcn_mfma_f32_32x32x16_bf16(kf[dc], qf0[dc], s0, 0, 0, 0);
        s1 = __builtin_amdgcn_mfma_f32_32x32x16_bf16(kf[dc], qf1[dc], s1, 0, 0, 0);
      }
#pragma unroll
      for (int kc = 0; kc < 2; ++kc) {
        bf16x8 vf0 = *(const bf16x8*)&sVp[off[kb * 2 + kc]];
        bf16x8 vf1 = *(const bf16x8*)&sVp[off[kb * 2 + kc] + 2048];
        SOFTPV(s0, r00, r01, r02, r03, o00, o01);
        SOFTPV(s1, r10, r11, r12, r13, o10, o11);
      }
    }
  };

  stage(kbase, 0);
  __syncthreads();

  for (int kt = kbase; kt < kend; kt += 128) {
    if (kt + 64 < kend) stage(kt + 64, 1);
    compute(sK[0], sV[0]);
    __syncthreads();
    if (kt + 128 < kend) stage(kt + 128, 0);
    compute(sK[1], sV[1]);
    __syncthreads();
  }

  float rsum0 = (r00 + r01) + (r02 + r03);
  rsum0 += __shfl_xor(rsum0, 32, 64);
  float rsum1 = (r10 + r11) + (r12 + r13);
  rsum1 += __shfl_xor(rsum1, 32, 64);

  if (SPLIT) {
    // Unnormalized O partials + rowsums; gemm_out_fused divides during staging.
    float* Oh = Op + ((size_t)(kh * BH + bh) * SEQ + q0w) * DH;
    if (hi == 0) {
      float* Rh = Rs + (size_t)(kh * BH + bh) * SEQ + q0w;
      Rh[l31]      = rsum0;
      Rh[32 + l31] = rsum1;
    }
#pragma unroll
    for (int i = 0; i < 16; ++i) {
      int ql = 8 * (i >> 2) + (i & 3) + 4 * hi;
      Oh[(size_t)ql * DH + l31]             = o00[i];
      Oh[(size_t)ql * DH + 32 + l31]        = o01[i];
      Oh[(size_t)(32 + ql) * DH + l31]      = o10[i];
      Oh[(size_t)(32 + ql) * DH + 32 + l31] = o11[i];
    }
  } else {
    float inv0 = 1.0f / rsum0;
    float inv1 = 1.0f / rsum1;
    const int bg = bh / NH, h = bh % NH;
#pragma unroll
    for (int i = 0; i < 16; ++i) {
      int ql = 8 * (i >> 2) + (i & 3) + 4 * hi;
      float iva = __shfl(inv0, ql, 64);          // bpermute from lane ql
      size_t basea = (size_t)(bg * SEQ + q0w + ql) * DM + h * DH;
      Oout[basea + l31]      = (bf16)(o00[i] * iva);
      Oout[basea + 32 + l31] = (bf16)(o01[i] * iva);
      float ivb = __shfl(inv1, ql, 64);
      size_t baseb = (size_t)(bg * SEQ + q0w + 32 + ql) * DM + h * DH;
      Oout[baseb + l31]      = (bf16)(o10[i] * ivb);
      Oout[baseb + 32 + l31] = (bf16)(o11[i] * ivb);
    }
  }
}

// ---------------------------------------------------------------- launcher
extern "C" void kernel_launch(void* const* d_in, const int* in_sizes, int n_in,
                              void* d_out, int out_size, void* d_ws, size_t ws_size,
                              hipStream_t stream) {
  const float* x     = (const float*)d_in[0];
  const float* qkv_w = (const float*)d_in[1];
  const float* qkv_b = (const float*)d_in[2];
  const float* out_w = (const float*)d_in[3];
  const float* out_b = (const float*)d_in[4];
  float* out = (float*)d_out;

  char* w = (char*)d_ws;
  bf16* xb    = (bf16*)w; w += (size_t)MT * DM * 2;
  bf16* wqkv  = (bf16*)w; w += (size_t)QKVN * DM * 2;
  bf16* wout  = (bf16*)w; w += (size_t)DM * DM * 2;
  bf16* Qw    = (bf16*)w; w += (size_t)MT * DM * 2;        // [bh][n][d], scaled 0.125*log2e
  bf16* Kw    = (bf16*)w; w += (size_t)MT * DM * 2;        // [bh][n][d]
  bf16* Vtw   = (bf16*)w; w += (size_t)MT * DM * 2;        // [bh][d][n]
  bf16* attnV = (bf16*)w; w += (size_t)MT * DM * 2;        // [m][768] (fallback only)
  float* Opf  = (float*)w; w += (size_t)2 * BH * SEQ * DH * 4;  // split-K O partials (f32)
  float* Rsf  = (float*)w; w += (size_t)2 * BH * SEQ * 4;       // split-K rowsums (f32)
  const size_t ws_need = (size_t)(w - (char*)d_ws);

  const int tot4 = NX4 + NW14 + NW24;
  cvt_all<<<dim3((tot4 + 255) / 256), 256, 0, stream>>>(x, qkv_w, out_w, xb, wqkv, wout);

  gemm_bt<0><<<dim3((QKVN / 128) * (MT / 128)), 256, 0, stream>>>(
      xb, wqkv, qkv_b, Qw, Kw, Vtw, nullptr, MT, QKVN, DM);

  if (ws_size >= ws_need) {
    // split-K path: flash partials -> out-proj GEMM with fused merge
    flash_attn<1><<<dim3(32, BH), 256, 0, stream>>>(Qw, Kw, Vtw, Opf, Rsf, nullptr);
    gemm_out_fused<<<dim3((DM / 128) * (MT / 128)), 256, 0, stream>>>(
        Opf, Rsf, wout, out_b, out);
  } else {
    // workspace-constrained fallback: single-pass flash -> plain out-proj GEMM
    flash_attn<0><<<dim3(16, BH), 256, 0, stream>>>(Qw, Kw, Vtw, nullptr, nullptr, attnV);
    gemm_bt<1><<<dim3((DM / 128) * (MT / 128)), 256, 0, stream>>>(
        attnV, wout, out_b, nullptr, nullptr, nullptr, out, MT, DM, DM);
  }
}

// Round 15
// 265.978 us; speedup vs baseline: 1.0348x; 1.0348x over previous
//
#include <hip/hip_runtime.h>
#include <cstdint>

#define SEQ 4096
#define NH 12
#define DH 64
#define DM 768
#define MT 8192      // B*SEQ
#define QKVN 2304    // 3*DM
#define BH 24        // B*NH

typedef __bf16 bf16;
typedef __attribute__((ext_vector_type(8))) __bf16 bf16x8;
typedef __attribute__((ext_vector_type(4))) __bf16 bf16x4;
typedef __attribute__((ext_vector_type(2))) __bf16 bf16x2;
typedef __attribute__((ext_vector_type(4))) float f32x4;
typedef __attribute__((ext_vector_type(16))) float f32x16;
typedef __attribute__((ext_vector_type(2))) int int2v;

// async global->LDS, 16B per lane. LDS dest is wave-uniform base + lane*16.
__device__ __forceinline__ void async_ld16(const void* g, void* lds) {
  __builtin_amdgcn_global_load_lds(
      (__attribute__((address_space(1))) void*)(void*)g,
      (__attribute__((address_space(3))) void*)lds, 16, 0, 0);
}

// Schraudolph exp2 in the f32-bit domain: bits = (int)(s*2^23 + 16252*65536).
// bits>>16 are the bf16(2^s) bits; bits&0xffff0000 reinterpreted as f32 is
// EXACTLY the bf16 P value — so the VALU rowsum matches PV's P bit-for-bit.
__device__ __forceinline__ int sexp2_bits(float s) {
  return (int)__builtin_fmaf(s, 8388608.0f, 1065091072.0f);
}

// pack {lo.hi16, hi.hi16} -> one dword (two bf16 lanes)
__device__ __forceinline__ int pack_hi16(int lo, int hi) {
#if __has_builtin(__builtin_amdgcn_perm)
  return (int)__builtin_amdgcn_perm((unsigned)hi, (unsigned)lo, 0x07060302u);
#else
  return (int)(((unsigned)lo >> 16) | ((unsigned)hi & 0xffff0000u));
#endif
}

// (a,b) -> a' = {a.lo32, b.lo32}, b' = {a.hi32, b.hi32}
__device__ __forceinline__ void lane32_swap(int& a, int& b) {
#if __has_builtin(__builtin_amdgcn_permlane32_swap)
  int2v r = __builtin_amdgcn_permlane32_swap(a, b, false, false);
  a = r.x; b = r.y;
#else
  int hi = (threadIdx.x & 63) >> 5;
  int ra = __shfl_xor(a, 32, 64), rb = __shfl_xor(b, 32, 64);
  int na = hi ? rb : a;
  int nb = hi ? b : ra;
  a = na; b = nb;
#endif
}

// ---------------------------------------------------------------- converts (merged)
#define NX4  (MT * DM / 4)
#define NW14 (QKVN * DM / 4)
#define NW24 (DM * DM / 4)
__global__ void cvt_all(const float* __restrict__ x, const float* __restrict__ w1,
                        const float* __restrict__ w2, bf16* __restrict__ xb,
                        bf16* __restrict__ wb1, bf16* __restrict__ wb2) {
  int i = blockIdx.x * blockDim.x + threadIdx.x;
  const float* src; bf16* dst; int j;
  if (i < NX4) { src = x; dst = xb; j = i; }
  else if (i < NX4 + NW14) { src = w1; dst = wb1; j = i - NX4; }
  else if (i < NX4 + NW14 + NW24) { src = w2; dst = wb2; j = i - NX4 - NW14; }
  else return;
  f32x4 v = ((const f32x4*)src)[j];
  bf16x4 o;
  o.x = (bf16)v.x; o.y = (bf16)v.y; o.z = (bf16)v.z; o.w = (bf16)v.w;
  ((bf16x4*)dst)[j] = o;
}

// ---------------------------------------------------------------- GEMM (B^T)
// C[M,N] = A[M,K] @ Bw[N,K]^T. 128x128 tile, BK=64, 4 waves, 64x64/wave.
// Global-side XOR granule swizzle; fragment reads g = G ^ (row&7), conflict-free.
// R30: XCD-pinned tile map. Grid (8*cpx blocks) remapped v=(bid%8)*cpx+bid/8
// (bijective) so XCD x owns ONE 8-M-tile supergroup x all N-tiles:
// B-panel (gemm0 3.4MB / gemm1 1.1MB) + A-supergroup (1.5MB) ~ L2-resident
// per XCD instead of 8x duplicated across XCDs (442MB of tile reads move
// from L3 to L2 speed). Within a supergroup order is n-major, 8-m-inner —
// same arithmetic as before with lin->v.
// R28 (kept): Q/K epilogue LDS-bounce -> coalesced bf16x8 stores.
// MODE 0: QKV epilogue -> +bias, Q(*0.125*log2e)/K as [bh][n][d]; V^T -> [bh][d][n]
// MODE 1: out-proj epilogue -> +bias, fp32 row-major [M,N]
template<int MODE>
__global__ __launch_bounds__(256) void gemm_bt(
    const bf16* __restrict__ A, const bf16* __restrict__ Bw,
    const float* __restrict__ bias,
    bf16* __restrict__ outQ, bf16* __restrict__ outK, bf16* __restrict__ outVt,
    float* __restrict__ outF,
    int M, int N, int K)
{
  __shared__ bf16 smem[2 * 128 * 64];   // sA | sB ; sT aliases the front
  bf16* sA = smem;
  bf16* sB = smem + 128 * 64;
  bf16* sT = smem;                      // reused only after the final K-loop barrier

  const int tid  = threadIdx.x;
  const int wave = tid >> 6;
  const int lane = tid & 63;
  const int l15  = lane & 15;
  const int quad = lane >> 4;

  constexpr int NT = (MODE == 0) ? (QKVN / 128) : (DM / 128);
  constexpr int CPX = NT * 8;                    // blocks per XCD supergroup
  const int lin = blockIdx.x;
  const int v   = (lin & 7) * CPX + (lin >> 3);  // XCD-pin remap (grid = 8*CPX)
  const int rem = v % CPX;
  const int m0 = ((v / CPX) * 8 + (rem % 8)) * 128;
  const int n0 = (rem / 8) * 128;

  const int rowbase = (wave >> 1) * 64;
  const int colbase = (wave & 1) * 64;

  f32x4 acc[4][4] = {};

  const int srow = lane >> 3;            // row within 8-row chunk
  const int spg  = (lane & 7) ^ srow;    // swizzled 16B granule within 128B row
  const int xk   = l15 & 7;              // fragment-read swizzle key

  for (int kt = 0; kt < K; kt += 64) {
#pragma unroll
    for (int p = 0; p < 8; ++p) {
      int chunk = p * 4 + wave;
      if (chunk < 16) {
        int row = chunk * 8 + srow;
        async_ld16(A + (size_t)(m0 + row) * K + kt + spg * 8, &sA[chunk * 512]);
      } else {
        int row = (chunk - 16) * 8 + srow;
        async_ld16(Bw + (size_t)(n0 + row) * K + kt + spg * 8, &sB[(chunk - 16) * 512]);
      }
    }
    __syncthreads();

#pragma unroll
    for (int ks = 0; ks < 2; ++ks) {
      bf16x8 af[4], bfr[4];
#pragma unroll
      for (int rt = 0; rt < 4; ++rt)
        af[rt] = *(const bf16x8*)&sA[(rowbase + rt * 16 + l15) * 64 +
                                     (((ks * 4 + quad) ^ xk) * 8)];
#pragma unroll
      for (int ct = 0; ct < 4; ++ct)
        bfr[ct] = *(const bf16x8*)&sB[(colbase + ct * 16 + l15) * 64 +
                                      (((ks * 4 + quad) ^ xk) * 8)];
#pragma unroll
      for (int rt = 0; rt < 4; ++rt)
#pragma unroll
        for (int ct = 0; ct < 4; ++ct)
          acc[rt][ct] = __builtin_amdgcn_mfma_f32_16x16x32_bf16(af[rt], bfr[ct], acc[rt][ct], 0, 0, 0);
    }
    __syncthreads();
  }

  if (MODE == 0) {
    const int g = n0 / DM;                       // uniform per block (0=q,1=k,2=v)
    if (g < 2) {
      // Q/K: LDS bounce sT[m][72] -> coalesced bf16x8 stores along d
      const float sc = (g == 0) ? 0.125f * 1.4426950408889634f : 1.0f;
      bf16* outQK = (g == 0) ? outQ : outK;
      const int f0q = n0 - g * DM;               // offset within the 768-wide group
      const int b = m0 >> 12, n0m = m0 & 4095;   // tile lies within one batch
#pragma unroll
      for (int p = 0; p < 2; ++p) {
        __syncthreads();
        if (colbase == p * 64) {
#pragma unroll
          for (int ct = 0; ct < 4; ++ct) {
            int c = ct * 16 + l15;
            float bj = bias[n0 + p * 64 + c];
#pragma unroll
            for (int rt = 0; rt < 4; ++rt) {
              int ml = rowbase + rt * 16 + quad * 4;
#pragma unroll
              for (int r = 0; r < 4; ++r)
                sT[(ml + r) * 72 + c] = (bf16)((acc[rt][ct][r] + bj) * sc);
            }
          }
        }
        __syncthreads();
        const int h = (f0q + p * 64) >> 6;
        const int bh = b * NH + h;
#pragma unroll
        for (int p2 = 0; p2 < 4; ++p2) {
          int slot = p2 * 256 + tid;
          int mr = slot >> 3, cg = slot & 7;
          *(bf16x8*)&outQK[((size_t)bh * SEQ + n0m + mr) * DH + cg * 8] =
              *(const bf16x8*)&sT[mr * 72 + cg * 8];
        }
      }
    } else {
      // V block: bounce through LDS, store V^T coalesced along n
      const int f0 = n0 - 2 * DM;
      const int b = m0 >> 12, n0m = m0 & 4095;
#pragma unroll
      for (int p = 0; p < 2; ++p) {
        __syncthreads();
        if (colbase == p * 64) {
#pragma unroll
          for (int ct = 0; ct < 4; ++ct) {
            int jl = ct * 16 + l15;
            float bj = bias[n0 + p * 64 + jl];
#pragma unroll
            for (int rt = 0; rt < 4; ++rt) {
              int ml = rowbase + rt * 16 + quad * 4;
#pragma unroll
              for (int r = 0; r < 4; ++r)
                sT[jl * 136 + ml + r] = (bf16)(acc[rt][ct][r] + bj);
            }
          }
        }
        __syncthreads();
#pragma unroll
        for (int p2 = 0; p2 < 4; ++p2) {
          int slot = p2 * 256 + tid;
          int jr = slot >> 4, mc = (slot & 15) * 8;
          int fj = f0 + p * 64 + jr;
          int h = fj >> 6, d = fj & 63;
          *(bf16x8*)&outVt[((size_t)(b * NH + h) * DH + d) * SEQ + n0m + mc] =
              *(const bf16x8*)&sT[jr * 136 + mc];
        }
      }
    }
  } else {
#pragma unroll
    for (int ct = 0; ct < 4; ++ct) {
      int j = n0 + colbase + ct * 16 + l15;
      float bj = bias[j];
#pragma unroll
      for (int rt = 0; rt < 4; ++rt) {
        int mrow = m0 + rowbase + rt * 16 + quad * 4;
#pragma unroll
        for (int r = 0; r < 4; ++r)
          outF[(size_t)(mrow + r) * N + j] = acc[rt][ct][r] + bj;
      }
    }
  }
}

// ---------------------------------------------------------------- flash attention v19
// R24 (measured round 12): 123.0 us, VGPR 128, zero spill, split-K even
// 768 blocks. Plateau note: v15 (2x LDS traffic) 127.7, R16 (-20% MFMA) 127.4,
// R24 123.0 — flash is stall-bound (~70% unaccounted cycles), not pipe-bound.
// Untouched this round. (R28's merge-fusion REVERTED: sync A-merge loads in
// the K-loop cost ~25us of exposed latency — measured +9.8 total.)
#define SOFTPV(S, R0, R1, R2, R3, OA, OB) do {                               \
    int b0 = sexp2_bits(S[8*kc+0]); int b1 = sexp2_bits(S[8*kc+1]);          \
    int b2 = sexp2_bits(S[8*kc+2]); int b3 = sexp2_bits(S[8*kc+3]);          \
    int b4 = sexp2_bits(S[8*kc+4]); int b5 = sexp2_bits(S[8*kc+5]);          \
    int b6 = sexp2_bits(S[8*kc+6]); int b7 = sexp2_bits(S[8*kc+7]);          \
    R0 += __int_as_float(b0 & 0xffff0000) + __int_as_float(b4 & 0xffff0000); \
    R1 += __int_as_float(b1 & 0xffff0000) + __int_as_float(b5 & 0xffff0000); \
    R2 += __int_as_float(b2 & 0xffff0000) + __int_as_float(b6 & 0xffff0000); \
    R3 += __int_as_float(b3 & 0xffff0000) + __int_as_float(b7 & 0xffff0000); \
    int g0a = pack_hi16(b0, b1), g0b = pack_hi16(b2, b3);                    \
    int g1a = pack_hi16(b4, b5), g1b = pack_hi16(b6, b7);                    \
    lane32_swap(g0a, g1a); lane32_swap(g0b, g1b);                            \
    union { int i[4]; bf16x8 v; } Af_;                                       \
    Af_.i[0] = g0a; Af_.i[1] = g0b; Af_.i[2] = g1a; Af_.i[3] = g1b;          \
    OA = __builtin_amdgcn_mfma_f32_32x32x16_bf16(Af_.v, vf0, OA, 0, 0, 0);   \
    OB = __builtin_amdgcn_mfma_f32_32x32x16_bf16(Af_.v, vf1, OB, 0, 0, 0);   \
  } while (0)

template<int SPLIT>
__global__ __launch_bounds__(256, 2) void flash_attn(
    const bf16* __restrict__ Q, const bf16* __restrict__ Kg,
    const bf16* __restrict__ Vt, float* __restrict__ Op,
    float* __restrict__ Rs, bf16* __restrict__ Oout)
{
  __shared__ bf16 sK[2][64 * 64];    // [key][d], granule-swizzled
  __shared__ bf16 sV[2][64 * 64];    // [d][key], granule-swizzled

  int bh, qb, kh;
  if (SPLIT) {
    const int L    = blockIdx.x + 32 * blockIdx.y;          // 0..767
    const int slot = L >> 3;                                // 0..95
    bh = (L & 7) + 8 * (slot >> 5);
    qb = (slot & 31) >> 1;
    kh = slot & 1;
  } else {
    const int L    = blockIdx.x + 16 * blockIdx.y;          // 0..383
    const int slot = L >> 3;                                // 0..47
    bh = (L & 7) + 8 * (slot >> 4);
    qb = slot & 15;
    kh = 0;
  }

  {
    int ph = (qb + bh + kh) & 3;
    if (ph == 1) __builtin_amdgcn_s_sleep(2);
    else if (ph == 2) __builtin_amdgcn_s_sleep(4);
    else if (ph == 3) __builtin_amdgcn_s_sleep(6);
  }

  const int tid  = threadIdx.x;
  const int wave = tid >> 6;
  const int lane = tid & 63;
  const int l31  = lane & 31;
  const int hi   = lane >> 5;
  const int q0w  = qb * 256 + wave * 64;    // 64 q-rows per wave (two 32-row sets)
  const int kbase = SPLIT ? kh * (SEQ / 2) : 0;
  const int kend  = SPLIT ? kbase + SEQ / 2 : SEQ;

  const bf16* Qb = Q  + (size_t)bh * SEQ * DH;
  const bf16* Kb = Kg + (size_t)bh * SEQ * DH;
  const bf16* Vb = Vt + (size_t)bh * DH * SEQ;

  const int srow = lane >> 3;
  const int spg  = lane & 7;

  bf16x8 qf0[4], qf1[4];
#pragma unroll
  for (int dc = 0; dc < 4; ++dc) {
    qf0[dc] = *(const bf16x8*)&Qb[(size_t)(q0w + l31) * DH + dc * 16 + hi * 8];
    qf1[dc] = *(const bf16x8*)&Qb[(size_t)(q0w + 32 + l31) * DH + dc * 16 + hi * 8];
  }

  f32x16 o00 = {}, o01 = {}, o10 = {}, o11 = {};
  const f32x16 zc = {};
  float r00 = 0.f, r01 = 0.f, r02 = 0.f, r03 = 0.f;
  float r10 = 0.f, r11 = 0.f, r12 = 0.f, r13 = 0.f;

  const int keyk = (l31 & 7) ^ (((l31 >> 3) & 3) << 1);
  int off[4];                       // shared K/V fragment offsets (identical maps)
#pragma unroll
  for (int dc = 0; dc < 4; ++dc)
    off[dc] = l31 * 64 + (((dc * 2 + hi) ^ keyk) * 8);

  auto stage = [&](int kt, int buf) {
#pragma unroll
    for (int j = 0; j < 2; ++j) {
      int r0 = wave * 16 + j * 8;
      int row = r0 + srow;
      int lg = spg ^ (row & 7) ^ (((row >> 3) & 3) << 1);
      async_ld16(Kb + (size_t)(kt + row) * DH + lg * 8, &sK[buf][r0 * 64]);
      async_ld16(Vb + (size_t)row * SEQ + kt + lg * 8, &sV[buf][r0 * 64]);
    }
  };

  auto compute = [&](const bf16* sKp, const bf16* sVp) {
#pragma unroll
    for (int kb = 0; kb < 2; ++kb) {
      bf16x8 kf[4];
#pragma unroll
      for (int dc = 0; dc < 4; ++dc)
        kf[dc] = *(const bf16x8*)&sKp[off[dc] + kb * 2048];
      f32x16 s0 = __builtin_amdgcn_mfma_f32_32x32x16_bf16(kf[0], qf0[0], zc, 0, 0, 0);
      f32x16 s1 = __builtin_amdgcn_mfma_f32_32x32x16_bf16(kf[0], qf1[0], zc, 0, 0, 0);
#pragma unroll
      for (int dc = 1; dc < 4; ++dc) {
        s0 = __builtin_amdgcn_mfma_f32_32x32x16_bf16(kf[dc], qf0[dc], s0, 0, 0, 0);
        s1 = __builtin_amdgcn_mfma_f32_32x32x16_bf16(kf[dc], qf1[dc], s1, 0, 0, 0);
      }
#pragma unroll
      for (int kc = 0; kc < 2; ++kc) {
        bf16x8 vf0 = *(const bf16x8*)&sVp[off[kb * 2 + kc]];
        bf16x8 vf1 = *(const bf16x8*)&sVp[off[kb * 2 + kc] + 2048];
        SOFTPV(s0, r00, r01, r02, r03, o00, o01);
        SOFTPV(s1, r10, r11, r12, r13, o10, o11);
      }
    }
  };

  stage(kbase, 0);
  __syncthreads();

  for (int kt = kbase; kt < kend; kt += 128) {
    if (kt + 64 < kend) stage(kt + 64, 1);
    compute(sK[0], sV[0]);
    __syncthreads();
    if (kt + 128 < kend) stage(kt + 128, 0);
    compute(sK[1], sV[1]);
    __syncthreads();
  }

  float rsum0 = (r00 + r01) + (r02 + r03);
  rsum0 += __shfl_xor(rsum0, 32, 64);
  float rsum1 = (r10 + r11) + (r12 + r13);
  rsum1 += __shfl_xor(rsum1, 32, 64);

  if (SPLIT) {
    // Unnormalized O partials + rowsums; merge_halves divides.
    float* Oh = Op + ((size_t)(kh * BH + bh) * SEQ + q0w) * DH;
    if (hi == 0) {
      float* Rh = Rs + (size_t)(kh * BH + bh) * SEQ + q0w;
      Rh[l31]      = rsum0;
      Rh[32 + l31] = rsum1;
    }
#pragma unroll
    for (int i = 0; i < 16; ++i) {
      int ql = 8 * (i >> 2) + (i & 3) + 4 * hi;
      Oh[(size_t)ql * DH + l31]             = o00[i];
      Oh[(size_t)ql * DH + 32 + l31]        = o01[i];
      Oh[(size_t)(32 + ql) * DH + l31]      = o10[i];
      Oh[(size_t)(32 + ql) * DH + 32 + l31] = o11[i];
    }
  } else {
    float inv0 = 1.0f / rsum0;
    float inv1 = 1.0f / rsum1;
    const int bg = bh / NH, h = bh % NH;
#pragma unroll
    for (int i = 0; i < 16; ++i) {
      int ql = 8 * (i >> 2) + (i & 3) + 4 * hi;
      float iva = __shfl(inv0, ql, 64);          // bpermute from lane ql
      size_t basea = (size_t)(bg * SEQ + q0w + ql) * DM + h * DH;
      Oout[basea + l31]      = (bf16)(o00[i] * iva);
      Oout[basea + 32 + l31] = (bf16)(o01[i] * iva);
      float ivb = __shfl(inv1, ql, 64);
      size_t baseb = (size_t)(bg * SEQ + q0w + 32 + ql) * DM + h * DH;
      Oout[baseb + l31]      = (bf16)(o10[i] * ivb);
      Oout[baseb + 32 + l31] = (bf16)(o11[i] * ivb);
    }
  }
}

// ---------------------------------------------------------------- split-K merge
// attnV[bg*SEQ+q][h*DH+d] = (O0+O1)/(r0+r1), f32 partials -> bf16.
// (Restored from R24 — measured config. R28's in-GEMM fusion regressed.)
__global__ __launch_bounds__(256) void merge_halves(
    const float* __restrict__ Op, const float* __restrict__ Rs,
    bf16* __restrict__ attnV)
{
  int i = blockIdx.x * 256 + threadIdx.x;        // one f32x4 (4 d-elems) per thread
  if (i >= BH * SEQ * (DH / 4)) return;
  int dq = i & 15, row = i >> 4;                 // row = bh*SEQ + q
  f32x4 a = ((const f32x4*)Op)[(size_t)row * 16 + dq];
  f32x4 b = ((const f32x4*)Op)[((size_t)BH * SEQ + row) * 16 + dq];
  float inv = 1.0f / (Rs[row] + Rs[BH * SEQ + row]);
  int q = row & (SEQ - 1), bh = row >> 12;
  int bg = bh / NH, h = bh % NH;
  bf16x4 r;
  r.x = (bf16)((a.x + b.x) * inv);
  r.y = (bf16)((a.y + b.y) * inv);
  r.z = (bf16)((a.z + b.z) * inv);
  r.w = (bf16)((a.w + b.w) * inv);
  *(bf16x4*)&attnV[((size_t)(bg * SEQ + q)) * DM + h * DH + dq * 4] = r;
}

// ---------------------------------------------------------------- launcher
extern "C" void kernel_launch(void* const* d_in, const int* in_sizes, int n_in,
                              void* d_out, int out_size, void* d_ws, size_t ws_size,
                              hipStream_t stream) {
  const float* x     = (const float*)d_in[0];
  const float* qkv_w = (const float*)d_in[1];
  const float* qkv_b = (const float*)d_in[2];
  const float* out_w = (const float*)d_in[3];
  const float* out_b = (const float*)d_in[4];
  float* out = (float*)d_out;

  char* w = (char*)d_ws;
  bf16* xb    = (bf16*)w; w += (size_t)MT * DM * 2;
  bf16* wqkv  = (bf16*)w; w += (size_t)QKVN * DM * 2;
  bf16* wout  = (bf16*)w; w += (size_t)DM * DM * 2;
  bf16* Qw    = (bf16*)w; w += (size_t)MT * DM * 2;        // [bh][n][d], scaled 0.125*log2e
  bf16* Kw    = (bf16*)w; w += (size_t)MT * DM * 2;        // [bh][n][d]
  bf16* Vtw   = (bf16*)w; w += (size_t)MT * DM * 2;        // [bh][d][n]
  bf16* attnV = (bf16*)w; w += (size_t)MT * DM * 2;        // [m][768]
  float* Opf  = (float*)w; w += (size_t)2 * BH * SEQ * DH * 4;  // split-K O partials (f32)
  float* Rsf  = (float*)w; w += (size_t)2 * BH * SEQ * 4;       // split-K rowsums (f32)
  const size_t ws_need = (size_t)(w - (char*)d_ws);

  const int tot4 = NX4 + NW14 + NW24;
  cvt_all<<<dim3((tot4 + 255) / 256), 256, 0, stream>>>(x, qkv_w, out_w, xb, wqkv, wout);

  gemm_bt<0><<<dim3((QKVN / 128) * (MT / 128)), 256, 0, stream>>>(
      xb, wqkv, qkv_b, Qw, Kw, Vtw, nullptr, MT, QKVN, DM);

  if (ws_size >= ws_need) {
    // split-K path: 768 blocks = 3/CU even, + merge
    flash_attn<1><<<dim3(32, BH), 256, 0, stream>>>(Qw, Kw, Vtw, Opf, Rsf, nullptr);
    merge_halves<<<dim3(BH * SEQ * (DH / 4) / 256), 256, 0, stream>>>(Opf, Rsf, attnV);
  } else {
    // workspace-constrained fallback: single-pass, writes attnV directly
    flash_attn<0><<<dim3(16, BH), 256, 0, stream>>>(Qw, Kw, Vtw, nullptr, nullptr, attnV);
  }

  gemm_bt<1><<<dim3((DM / 128) * (MT / 128)), 256, 0, stream>>>(
      attnV, wout, out_b, nullptr, nullptr, nullptr, out, MT, DM, DM);
}

// Round 16
// 257.487 us; speedup vs baseline: 1.0690x; 1.0330x over previous
//
#include <hip/hip_runtime.h>
#include <cstdint>

#define SEQ 4096
#define NH 12
#define DH 64
#define DM 768
#define MT 8192      // B*SEQ
#define QKVN 2304    // 3*DM
#define BH 24        // B*NH

typedef __bf16 bf16;
typedef __attribute__((ext_vector_type(8))) __bf16 bf16x8;
typedef __attribute__((ext_vector_type(4))) __bf16 bf16x4;
typedef __attribute__((ext_vector_type(2))) __bf16 bf16x2;
typedef __attribute__((ext_vector_type(4))) float f32x4;
typedef __attribute__((ext_vector_type(16))) float f32x16;
typedef __attribute__((ext_vector_type(2))) int int2v;

// async global->LDS, 16B per lane. LDS dest is wave-uniform base + lane*16.
__device__ __forceinline__ void async_ld16(const void* g, void* lds) {
  __builtin_amdgcn_global_load_lds(
      (__attribute__((address_space(1))) void*)(void*)g,
      (__attribute__((address_space(3))) void*)lds, 16, 0, 0);
}

// Schraudolph exp2 in the f32-bit domain: bits = (int)(s*2^23 + 16252*65536).
// bits>>16 are the bf16(2^s) bits; bits&0xffff0000 reinterpreted as f32 is
// EXACTLY the bf16 P value — so the VALU rowsum matches PV's P bit-for-bit.
__device__ __forceinline__ int sexp2_bits(float s) {
  return (int)__builtin_fmaf(s, 8388608.0f, 1065091072.0f);
}

// pack {lo.hi16, hi.hi16} -> one dword (two bf16 lanes)
__device__ __forceinline__ int pack_hi16(int lo, int hi) {
#if __has_builtin(__builtin_amdgcn_perm)
  return (int)__builtin_amdgcn_perm((unsigned)hi, (unsigned)lo, 0x07060302u);
#else
  return (int)(((unsigned)lo >> 16) | ((unsigned)hi & 0xffff0000u));
#endif
}

// (a,b) -> a' = {a.lo32, b.lo32}, b' = {a.hi32, b.hi32}
__device__ __forceinline__ void lane32_swap(int& a, int& b) {
#if __has_builtin(__builtin_amdgcn_permlane32_swap)
  int2v r = __builtin_amdgcn_permlane32_swap(a, b, false, false);
  a = r.x; b = r.y;
#else
  int hi = (threadIdx.x & 63) >> 5;
  int ra = __shfl_xor(a, 32, 64), rb = __shfl_xor(b, 32, 64);
  int na = hi ? rb : a;
  int nb = hi ? b : ra;
  a = na; b = nb;
#endif
}

// ---------------------------------------------------------------- converts (merged)
#define NX4  (MT * DM / 4)
#define NW14 (QKVN * DM / 4)
#define NW24 (DM * DM / 4)
__global__ void cvt_all(const float* __restrict__ x, const float* __restrict__ w1,
                        const float* __restrict__ w2, bf16* __restrict__ xb,
                        bf16* __restrict__ wb1, bf16* __restrict__ wb2) {
  int i = blockIdx.x * blockDim.x + threadIdx.x;
  const float* src; bf16* dst; int j;
  if (i < NX4) { src = x; dst = xb; j = i; }
  else if (i < NX4 + NW14) { src = w1; dst = wb1; j = i - NX4; }
  else if (i < NX4 + NW14 + NW24) { src = w2; dst = wb2; j = i - NX4 - NW14; }
  else return;
  f32x4 v = ((const f32x4*)src)[j];
  bf16x4 o;
  o.x = (bf16)v.x; o.y = (bf16)v.y; o.z = (bf16)v.z; o.w = (bf16)v.w;
  ((bf16x4*)dst)[j] = o;
}

// ---------------------------------------------------------------- GEMM (B^T)
// C[M,N] = A[M,K] @ Bw[N,K]^T. 128x128 tile, BK=64, 4 waves, 64x64/wave.
// R31: 2-PHASE double-buffered K-loop (T3-minimum recipe). Old loop was
// 1-phase: issue loads -> __syncthreads (vmcnt(0) drain, ~700cy HBM latency
// EXPOSED) -> ~620cy compute -> barrier, x12 iters => staging latency
// serialized with compute (gemm pair ~100us vs 19us MFMA floor). New loop:
// stage(next->buf^1) BEFORE compute(buf); ONE barrier/iter drains the
// prefetch AFTER compute has run -> latency overlapped. LDS 2x32KB = 64KB
// (2 blocks/CU; within-block overlap replaces lost inter-block overlap —
// m230/m248: 2-phase at 128^2 = 622-682 TF).
// Global-side XOR granule swizzle; fragment reads g = G ^ (row&7), conflict-free.
// XCD-pinned tile map (R30, neutral-measured, kept). Q/K epilogue LDS-bounce
// -> coalesced bf16x8 stores (R28, neutral-measured, kept).
// MODE 0: QKV epilogue -> +bias, Q(*0.125*log2e)/K as [bh][n][d]; V^T -> [bh][d][n]
// MODE 1: out-proj epilogue -> +bias, fp32 row-major [M,N]
template<int MODE>
__global__ __launch_bounds__(256) void gemm_bt(
    const bf16* __restrict__ A, const bf16* __restrict__ Bw,
    const float* __restrict__ bias,
    bf16* __restrict__ outQ, bf16* __restrict__ outK, bf16* __restrict__ outVt,
    float* __restrict__ outF,
    int M, int N, int K)
{
  __shared__ bf16 smem[2 * 2 * 128 * 64];   // [buf][sA|sB] = 64 KB
  bf16* sT = smem;                          // epilogue bounce, aliases buf0

  const int tid  = threadIdx.x;
  const int wave = tid >> 6;
  const int lane = tid & 63;
  const int l15  = lane & 15;
  const int quad = lane >> 4;

  constexpr int NT = (MODE == 0) ? (QKVN / 128) : (DM / 128);
  constexpr int CPX = NT * 8;                    // blocks per XCD supergroup
  const int lin = blockIdx.x;
  const int v   = (lin & 7) * CPX + (lin >> 3);  // XCD-pin remap (grid = 8*CPX)
  const int rem = v % CPX;
  const int m0 = ((v / CPX) * 8 + (rem % 8)) * 128;
  const int n0 = (rem / 8) * 128;

  const int rowbase = (wave >> 1) * 64;
  const int colbase = (wave & 1) * 64;

  f32x4 acc[4][4] = {};

  const int srow = lane >> 3;            // row within 8-row chunk
  const int spg  = (lane & 7) ^ srow;    // swizzled 16B granule within 128B row
  const int xk   = l15 & 7;              // fragment-read swizzle key

  auto stageg = [&](int kt, int buf) {
    bf16* sA = smem + buf * 16384;
    bf16* sB = sA + 8192;
#pragma unroll
    for (int p = 0; p < 8; ++p) {
      int chunk = p * 4 + wave;
      if (chunk < 16) {
        int row = chunk * 8 + srow;
        async_ld16(A + (size_t)(m0 + row) * K + kt + spg * 8, &sA[chunk * 512]);
      } else {
        int row = (chunk - 16) * 8 + srow;
        async_ld16(Bw + (size_t)(n0 + row) * K + kt + spg * 8, &sB[(chunk - 16) * 512]);
      }
    }
  };

  auto computeg = [&](int buf) {
    const bf16* sA = smem + buf * 16384;
    const bf16* sB = sA + 8192;
#pragma unroll
    for (int ks = 0; ks < 2; ++ks) {
      bf16x8 af[4], bfr[4];
#pragma unroll
      for (int rt = 0; rt < 4; ++rt)
        af[rt] = *(const bf16x8*)&sA[(rowbase + rt * 16 + l15) * 64 +
                                     (((ks * 4 + quad) ^ xk) * 8)];
#pragma unroll
      for (int ct = 0; ct < 4; ++ct)
        bfr[ct] = *(const bf16x8*)&sB[(colbase + ct * 16 + l15) * 64 +
                                      (((ks * 4 + quad) ^ xk) * 8)];
#pragma unroll
      for (int rt = 0; rt < 4; ++rt)
#pragma unroll
        for (int ct = 0; ct < 4; ++ct)
          acc[rt][ct] = __builtin_amdgcn_mfma_f32_16x16x32_bf16(af[rt], bfr[ct], acc[rt][ct], 0, 0, 0);
    }
  };

  // 2-phase pipeline: prefetch of tile t+1 is in flight DURING compute of t;
  // the single __syncthreads per iter (implicit vmcnt(0)+lgkmcnt(0)) lands
  // after compute, so HBM latency hides under the MFMA burst.
  stageg(0, 0);
  __syncthreads();
  int buf = 0;
  for (int kt = 64; kt < K; kt += 64) {
    stageg(kt, buf ^ 1);
    computeg(buf);
    __syncthreads();
    buf ^= 1;
  }
  computeg(buf);

  if (MODE == 0) {
    const int g = n0 / DM;                       // uniform per block (0=q,1=k,2=v)
    if (g < 2) {
      // Q/K: LDS bounce sT[m][72] -> coalesced bf16x8 stores along d
      const float sc = (g == 0) ? 0.125f * 1.4426950408889634f : 1.0f;
      bf16* outQK = (g == 0) ? outQ : outK;
      const int f0q = n0 - g * DM;               // offset within the 768-wide group
      const int b = m0 >> 12, n0m = m0 & 4095;   // tile lies within one batch
#pragma unroll
      for (int p = 0; p < 2; ++p) {
        __syncthreads();
        if (colbase == p * 64) {
#pragma unroll
          for (int ct = 0; ct < 4; ++ct) {
            int c = ct * 16 + l15;
            float bj = bias[n0 + p * 64 + c];
#pragma unroll
            for (int rt = 0; rt < 4; ++rt) {
              int ml = rowbase + rt * 16 + quad * 4;
#pragma unroll
              for (int r = 0; r < 4; ++r)
                sT[(ml + r) * 72 + c] = (bf16)((acc[rt][ct][r] + bj) * sc);
            }
          }
        }
        __syncthreads();
        const int h = (f0q + p * 64) >> 6;
        const int bh = b * NH + h;
#pragma unroll
        for (int p2 = 0; p2 < 4; ++p2) {
          int slot = p2 * 256 + tid;
          int mr = slot >> 3, cg = slot & 7;
          *(bf16x8*)&outQK[((size_t)bh * SEQ + n0m + mr) * DH + cg * 8] =
              *(const bf16x8*)&sT[mr * 72 + cg * 8];
        }
      }
    } else {
      // V block: bounce through LDS, store V^T coalesced along n
      const int f0 = n0 - 2 * DM;
      const int b = m0 >> 12, n0m = m0 & 4095;
#pragma unroll
      for (int p = 0; p < 2; ++p) {
        __syncthreads();
        if (colbase == p * 64) {
#pragma unroll
          for (int ct = 0; ct < 4; ++ct) {
            int jl = ct * 16 + l15;
            float bj = bias[n0 + p * 64 + jl];
#pragma unroll
            for (int rt = 0; rt < 4; ++rt) {
              int ml = rowbase + rt * 16 + quad * 4;
#pragma unroll
              for (int r = 0; r < 4; ++r)
                sT[jl * 136 + ml + r] = (bf16)(acc[rt][ct][r] + bj);
            }
          }
        }
        __syncthreads();
#pragma unroll
        for (int p2 = 0; p2 < 4; ++p2) {
          int slot = p2 * 256 + tid;
          int jr = slot >> 4, mc = (slot & 15) * 8;
          int fj = f0 + p * 64 + jr;
          int h = fj >> 6, d = fj & 63;
          *(bf16x8*)&outVt[((size_t)(b * NH + h) * DH + d) * SEQ + n0m + mc] =
              *(const bf16x8*)&sT[jr * 136 + mc];
        }
      }
    }
  } else {
#pragma unroll
    for (int ct = 0; ct < 4; ++ct) {
      int j = n0 + colbase + ct * 16 + l15;
      float bj = bias[j];
#pragma unroll
      for (int rt = 0; rt < 4; ++rt) {
        int mrow = m0 + rowbase + rt * 16 + quad * 4;
#pragma unroll
        for (int r = 0; r < 4; ++r)
          outF[(size_t)(mrow + r) * N + j] = acc[rt][ct][r] + bj;
      }
    }
  }
}

// ---------------------------------------------------------------- flash attention v15 (restored)
// R31: restored round-3 measured config (127.4us, VGPR 80, zero spill,
// 768 blocks = 3/CU even, 32q/wave, single pass, writes attnV directly).
// Campaign accounting: split-K flash (125us) + merge (~14us) = 139us — a net
// LOSS vs this 127.4. Split-K experiment closed: the flash plateau (123-128
// across 2x LDS-traffic / -20% MFMA / split variants) is stall-bound
// structure, and the merge pass can't pay for itself.
__global__ __launch_bounds__(256, 3) void flash_attn(
    const bf16* __restrict__ Q, const bf16* __restrict__ Kg,
    const bf16* __restrict__ Vt, bf16* __restrict__ Oout)
{
  __shared__ bf16 sK[2][64 * 64];    // [key][d], granule-swizzled
  __shared__ bf16 sV[2][64 * 64];    // [d][key], granule-swizzled

  // XCD-aware remap: xcd = L%8 owns heads {X, X+8, X+16}; 32 q-blocks/head.
  const int L    = blockIdx.x + (SEQ / 128) * blockIdx.y;   // 0..767
  const int xcd  = L & 7;
  const int slot = L >> 3;                                  // 0..95
  const int bh   = xcd + 8 * (slot >> 5);                   // 0..23
  const int qb   = slot & 31;

  {
    int ph = (qb + bh) & 3;
    if (ph == 1) __builtin_amdgcn_s_sleep(2);
    else if (ph == 2) __builtin_amdgcn_s_sleep(4);
    else if (ph == 3) __builtin_amdgcn_s_sleep(6);
  }

  const int tid  = threadIdx.x;
  const int wave = tid >> 6;
  const int lane = tid & 63;
  const int l31  = lane & 31;
  const int hi   = lane >> 5;
  const int q0w = qb * 128 + wave * 32;

  const bf16* Qb = Q  + (size_t)bh * SEQ * DH;
  const bf16* Kb = Kg + (size_t)bh * SEQ * DH;
  const bf16* Vb = Vt + (size_t)bh * DH * SEQ;

  const int srow = lane >> 3;
  const int spg  = lane & 7;

  bf16x8 qf[4];
#pragma unroll
  for (int dc = 0; dc < 4; ++dc)
    qf[dc] = *(const bf16x8*)&Qb[(size_t)(q0w + l31) * DH + dc * 16 + hi * 8];

  f32x16 o0 = {}, o1 = {};
  float rs0 = 0.f, rs1 = 0.f, rs2 = 0.f, rs3 = 0.f;   // f32 rowsum accumulators

  const int keyk = (l31 & 7) ^ (((l31 >> 3) & 3) << 1);
  int off[4];                       // shared K/V fragment offsets (identical maps)
#pragma unroll
  for (int dc = 0; dc < 4; ++dc)
    off[dc] = l31 * 64 + (((dc * 2 + hi) ^ keyk) * 8);

  auto stage = [&](int kt, int buf) {
#pragma unroll
    for (int j = 0; j < 2; ++j) {
      int r0 = wave * 16 + j * 8;
      int row = r0 + srow;
      int lg = spg ^ (row & 7) ^ (((row >> 3) & 3) << 1);
      async_ld16(Kb + (size_t)(kt + row) * DH + lg * 8, &sK[buf][r0 * 64]);
      async_ld16(Vb + (size_t)row * SEQ + kt + lg * 8, &sV[buf][r0 * 64]);
    }
  };

  auto compute = [&](const bf16* sKp, const bf16* sVp) {
#pragma unroll
    for (int kb = 0; kb < 2; ++kb) {
      f32x16 s = {};
#pragma unroll
      for (int dc = 0; dc < 4; ++dc) {
        bf16x8 kf = *(const bf16x8*)&sKp[off[dc] + kb * 2048];
        s = __builtin_amdgcn_mfma_f32_32x32x16_bf16(kf, qf[dc], s, 0, 0, 0);
      }
#pragma unroll
      for (int kc = 0; kc < 2; ++kc) {
        int b0 = sexp2_bits(s[8 * kc + 0]);
        int b1 = sexp2_bits(s[8 * kc + 1]);
        int b2 = sexp2_bits(s[8 * kc + 2]);
        int b3 = sexp2_bits(s[8 * kc + 3]);
        int b4 = sexp2_bits(s[8 * kc + 4]);
        int b5 = sexp2_bits(s[8 * kc + 5]);
        int b6 = sexp2_bits(s[8 * kc + 6]);
        int b7 = sexp2_bits(s[8 * kc + 7]);
        // rowsum of the EXACT bf16 P values (hi16 reinterpreted as f32)
        rs0 += __int_as_float(b0 & 0xffff0000) + __int_as_float(b4 & 0xffff0000);
        rs1 += __int_as_float(b1 & 0xffff0000) + __int_as_float(b5 & 0xffff0000);
        rs2 += __int_as_float(b2 & 0xffff0000) + __int_as_float(b6 & 0xffff0000);
        rs3 += __int_as_float(b3 & 0xffff0000) + __int_as_float(b7 & 0xffff0000);
        int g0a = pack_hi16(b0, b1);
        int g0b = pack_hi16(b2, b3);
        int g1a = pack_hi16(b4, b5);
        int g1b = pack_hi16(b6, b7);
        lane32_swap(g0a, g1a);
        lane32_swap(g0b, g1b);
        union { int i[4]; bf16x8 v; } Af;
        Af.i[0] = g0a; Af.i[1] = g0b; Af.i[2] = g1a; Af.i[3] = g1b;
        bf16x8 vf0 = *(const bf16x8*)&sVp[off[kb * 2 + kc]];
        bf16x8 vf1 = *(const bf16x8*)&sVp[off[kb * 2 + kc] + 2048];
        o0 = __builtin_amdgcn_mfma_f32_32x32x16_bf16(Af.v, vf0, o0, 0, 0, 0);
        o1 = __builtin_amdgcn_mfma_f32_32x32x16_bf16(Af.v, vf1, o1, 0, 0, 0);
      }
    }
  };

  stage(0, 0);
  __syncthreads();

  for (int kt = 0; kt < SEQ; kt += 128) {
    if (kt + 64 < SEQ) stage(kt + 64, 1);
    compute(sK[0], sV[0]);
    __syncthreads();
    if (kt + 128 < SEQ) stage(kt + 128, 0);
    compute(sK[1], sV[1]);
    __syncthreads();
  }

  // lane l holds the partial rowsum for q = l&31 over its hi-parity key subset;
  // the complementary subset lives on lane l^32.
  float rsum = (rs0 + rs1) + (rs2 + rs3);
  rsum += __shfl_xor(rsum, 32, 64);
  float invq = 1.0f / rsum;          // lane l: 1/sum for q-row (l&31)

  const int bg = bh / NH, h = bh % NH;
#pragma unroll
  for (int i = 0; i < 16; ++i) {
    int ql = 8 * (i >> 2) + (i & 3) + 4 * hi;
    float inv = __shfl(invq, ql, 64);          // bpermute from lane ql
    size_t base = (size_t)(bg * SEQ + q0w + ql) * DM + h * DH;
    Oout[base + l31]      = (bf16)(o0[i] * inv);
    Oout[base + 32 + l31] = (bf16)(o1[i] * inv);
  }
}

// ---------------------------------------------------------------- launcher
extern "C" void kernel_launch(void* const* d_in, const int* in_sizes, int n_in,
                              void* d_out, int out_size, void* d_ws, size_t ws_size,
                              hipStream_t stream) {
  const float* x     = (const float*)d_in[0];
  const float* qkv_w = (const float*)d_in[1];
  const float* qkv_b = (const float*)d_in[2];
  const float* out_w = (const float*)d_in[3];
  const float* out_b = (const float*)d_in[4];
  float* out = (float*)d_out;

  char* w = (char*)d_ws;
  bf16* xb    = (bf16*)w; w += (size_t)MT * DM * 2;
  bf16* wqkv  = (bf16*)w; w += (size_t)QKVN * DM * 2;
  bf16* wout  = (bf16*)w; w += (size_t)DM * DM * 2;
  bf16* Qw    = (bf16*)w; w += (size_t)MT * DM * 2;        // [bh][n][d], scaled 0.125*log2e
  bf16* Kw    = (bf16*)w; w += (size_t)MT * DM * 2;        // [bh][n][d]
  bf16* Vtw   = (bf16*)w; w += (size_t)MT * DM * 2;        // [bh][d][n]
  bf16* attnV = (bf16*)w; w += (size_t)MT * DM * 2;        // [m][768]

  const int tot4 = NX4 + NW14 + NW24;
  cvt_all<<<dim3((tot4 + 255) / 256), 256, 0, stream>>>(x, qkv_w, out_w, xb, wqkv, wout);

  gemm_bt<0><<<dim3((QKVN / 128) * (MT / 128)), 256, 0, stream>>>(
      xb, wqkv, qkv_b, Qw, Kw, Vtw, nullptr, MT, QKVN, DM);

  flash_attn<<<dim3(SEQ / 128, 2 * NH), 256, 0, stream>>>(Qw, Kw, Vtw, attnV);

  gemm_bt<1><<<dim3((DM / 128) * (MT / 128)), 256, 0, stream>>>(
      attnV, wout, out_b, nullptr, nullptr, nullptr, out, MT, DM, DM);
}

// Round 19
// 253.462 us; speedup vs baseline: 1.0860x; 1.0159x over previous
//
#include <hip/hip_runtime.h>
#include <cstdint>

#define SEQ 4096
#define NH 12
#define DH 64
#define DM 768
#define MT 8192      // B*SEQ
#define QKVN 2304    // 3*DM
#define BH 24        // B*NH

typedef __bf16 bf16;
typedef __attribute__((ext_vector_type(8))) __bf16 bf16x8;
typedef __attribute__((ext_vector_type(4))) __bf16 bf16x4;
typedef __attribute__((ext_vector_type(2))) __bf16 bf16x2;
typedef __attribute__((ext_vector_type(4))) float f32x4;
typedef __attribute__((ext_vector_type(16))) float f32x16;
typedef __attribute__((ext_vector_type(2))) int int2v;

// async global->LDS, 16B per lane. LDS dest is wave-uniform base + lane*16.
__device__ __forceinline__ void async_ld16(const void* g, void* lds) {
  __builtin_amdgcn_global_load_lds(
      (__attribute__((address_space(1))) void*)(void*)g,
      (__attribute__((address_space(3))) void*)lds, 16, 0, 0);
}

// Schraudolph exp2 in the f32-bit domain: bits = (int)(s*2^23 + 16252*65536).
// bits>>16 are the bf16(2^s) bits; bits&0xffff0000 reinterpreted as f32 is
// EXACTLY the bf16 P value — so the VALU rowsum matches PV's P bit-for-bit.
__device__ __forceinline__ int sexp2_bits(float s) {
  return (int)__builtin_fmaf(s, 8388608.0f, 1065091072.0f);
}

// pack {lo.hi16, hi.hi16} -> one dword (two bf16 lanes)
__device__ __forceinline__ int pack_hi16(int lo, int hi) {
#if __has_builtin(__builtin_amdgcn_perm)
  return (int)__builtin_amdgcn_perm((unsigned)hi, (unsigned)lo, 0x07060302u);
#else
  return (int)(((unsigned)lo >> 16) | ((unsigned)hi & 0xffff0000u));
#endif
}

// (a,b) -> a' = {a.lo32, b.lo32}, b' = {a.hi32, b.hi32}
__device__ __forceinline__ void lane32_swap(int& a, int& b) {
#if __has_builtin(__builtin_amdgcn_permlane32_swap)
  int2v r = __builtin_amdgcn_permlane32_swap(a, b, false, false);
  a = r.x; b = r.y;
#else
  int hi = (threadIdx.x & 63) >> 5;
  int ra = __shfl_xor(a, 32, 64), rb = __shfl_xor(b, 32, 64);
  int na = hi ? rb : a;
  int nb = hi ? b : ra;
  a = na; b = nb;
#endif
}

// ---------------------------------------------------------------- converts (merged)
#define NX4  (MT * DM / 4)
#define NW14 (QKVN * DM / 4)
#define NW24 (DM * DM / 4)
__global__ void cvt_all(const float* __restrict__ x, const float* __restrict__ w1,
                        const float* __restrict__ w2, bf16* __restrict__ xb,
                        bf16* __restrict__ wb1, bf16* __restrict__ wb2) {
  int i = blockIdx.x * blockDim.x + threadIdx.x;
  const float* src; bf16* dst; int j;
  if (i < NX4) { src = x; dst = xb; j = i; }
  else if (i < NX4 + NW14) { src = w1; dst = wb1; j = i - NX4; }
  else if (i < NX4 + NW14 + NW24) { src = w2; dst = wb2; j = i - NX4 - NW14; }
  else return;
  f32x4 v = ((const f32x4*)src)[j];
  bf16x4 o;
  o.x = (bf16)v.x; o.y = (bf16)v.y; o.z = (bf16)v.z; o.w = (bf16)v.w;
  ((bf16x4*)dst)[j] = o;
}

// ---------------------------------------------------------------- GEMM (B^T)
// C[M,N] = A[M,K] @ Bw[N,K]^T. 128x128 tile, BK=64, 4 waves, 64x64/wave.
// R32 (resubmitted R33/R34 after broker timeouts): depth-2 prefetch + COUNTED
// vmcnt (T4-minimum graft). R31's 2-phase gave loads only ONE compute phase
// (~620cy) vs ~700-900cy HBM latency, and __syncthreads still drained
// vmcnt(0) every iter. New loop: 2 tiles in flight; per iter {vmcnt(8) ->
// only tile t's 8 loads (per-wave FIFO) + s_barrier => tile t resident on
// all waves while t+1 stays IN FLIGHT; compute; s_barrier (all ds_reads
// retired via compiler lgkm waits before any wave passes); stage t+2 into
// the now-dead buffer}. Loads get two compute phases of cover; nothing
// drains to 0 mid-loop (m218: counted-vs-drain0 = +38-73% on the 8-phase;
// this is the minimum graft).
// Global-side XOR granule swizzle; fragment reads g = G ^ (row&7), conflict-free.
// XCD-pinned tile map (R30, neutral, kept). Q/K epilogue LDS-bounce (R28, kept).
// MODE 0: QKV epilogue -> +bias, Q(*0.125*log2e)/K as [bh][n][d]; V^T -> [bh][d][n]
// MODE 1: out-proj epilogue -> +bias, fp32 row-major [M,N]
template<int MODE>
__global__ __launch_bounds__(256) void gemm_bt(
    const bf16* __restrict__ A, const bf16* __restrict__ Bw,
    const float* __restrict__ bias,
    bf16* __restrict__ outQ, bf16* __restrict__ outK, bf16* __restrict__ outVt,
    float* __restrict__ outF,
    int M, int N, int K)
{
  __shared__ bf16 smem[2 * 2 * 128 * 64];   // [buf][sA|sB] = 64 KB
  bf16* sT = smem;                          // epilogue bounce, aliases buf0

  const int tid  = threadIdx.x;
  const int wave = tid >> 6;
  const int lane = tid & 63;
  const int l15  = lane & 15;
  const int quad = lane >> 4;

  constexpr int NT = (MODE == 0) ? (QKVN / 128) : (DM / 128);
  constexpr int CPX = NT * 8;                    // blocks per XCD supergroup
  const int lin = blockIdx.x;
  const int v   = (lin & 7) * CPX + (lin >> 3);  // XCD-pin remap (grid = 8*CPX)
  const int rem = v % CPX;
  const int m0 = ((v / CPX) * 8 + (rem % 8)) * 128;
  const int n0 = (rem / 8) * 128;

  const int rowbase = (wave >> 1) * 64;
  const int colbase = (wave & 1) * 64;

  f32x4 acc[4][4] = {};

  const int srow = lane >> 3;            // row within 8-row chunk
  const int spg  = (lane & 7) ^ srow;    // swizzled 16B granule within 128B row
  const int xk   = l15 & 7;              // fragment-read swizzle key

  auto stageg = [&](int kt, int buf) {
    bf16* sA = smem + buf * 16384;
    bf16* sB = sA + 8192;
#pragma unroll
    for (int p = 0; p < 8; ++p) {
      int chunk = p * 4 + wave;
      if (chunk < 16) {
        int row = chunk * 8 + srow;
        async_ld16(A + (size_t)(m0 + row) * K + kt + spg * 8, &sA[chunk * 512]);
      } else {
        int row = (chunk - 16) * 8 + srow;
        async_ld16(Bw + (size_t)(n0 + row) * K + kt + spg * 8, &sB[(chunk - 16) * 512]);
      }
    }
  };

  auto computeg = [&](int buf) {
    const bf16* sA = smem + buf * 16384;
    const bf16* sB = sA + 8192;
#pragma unroll
    for (int ks = 0; ks < 2; ++ks) {
      bf16x8 af[4], bfr[4];
#pragma unroll
      for (int rt = 0; rt < 4; ++rt)
        af[rt] = *(const bf16x8*)&sA[(rowbase + rt * 16 + l15) * 64 +
                                     (((ks * 4 + quad) ^ xk) * 8)];
#pragma unroll
      for (int ct = 0; ct < 4; ++ct)
        bfr[ct] = *(const bf16x8*)&sB[(colbase + ct * 16 + l15) * 64 +
                                      (((ks * 4 + quad) ^ xk) * 8)];
#pragma unroll
      for (int rt = 0; rt < 4; ++rt)
#pragma unroll
        for (int ct = 0; ct < 4; ++ct)
          acc[rt][ct] = __builtin_amdgcn_mfma_f32_16x16x32_bf16(af[rt], bfr[ct], acc[rt][ct], 0, 0, 0);
    }
  };

  const int nt = K >> 6;                   // 12 for K=768
  stageg(0, 0);
  if (nt > 1) stageg(64, 1);
  for (int t = 0; t < nt; ++t) {
    if (t + 1 < nt) {
      // wait for tile t's 8 loads (this wave); tile t+1's 8 remain in flight
      asm volatile("s_waitcnt vmcnt(8)" ::: "memory");
    } else {
      asm volatile("s_waitcnt vmcnt(0)" ::: "memory");
    }
    __builtin_amdgcn_sched_barrier(0);
    __builtin_amdgcn_s_barrier();          // tile t resident for ALL waves
    computeg(t & 1);
    __builtin_amdgcn_s_barrier();          // all waves done reading buf (t&1)
    __builtin_amdgcn_sched_barrier(0);
    if (t + 2 < nt) stageg((t + 2) * 64, t & 1);
  }

  if (MODE == 0) {
    const int g = n0 / DM;                       // uniform per block (0=q,1=k,2=v)
    if (g < 2) {
      // Q/K: LDS bounce sT[m][72] -> coalesced bf16x8 stores along d
      const float sc = (g == 0) ? 0.125f * 1.4426950408889634f : 1.0f;
      bf16* outQK = (g == 0) ? outQ : outK;
      const int f0q = n0 - g * DM;               // offset within the 768-wide group
      const int b = m0 >> 12, n0m = m0 & 4095;   // tile lies within one batch
#pragma unroll
      for (int p = 0; p < 2; ++p) {
        __syncthreads();
        if (colbase == p * 64) {
#pragma unroll
          for (int ct = 0; ct < 4; ++ct) {
            int c = ct * 16 + l15;
            float bj = bias[n0 + p * 64 + c];
#pragma unroll
            for (int rt = 0; rt < 4; ++rt) {
              int ml = rowbase + rt * 16 + quad * 4;
#pragma unroll
              for (int r = 0; r < 4; ++r)
                sT[(ml + r) * 72 + c] = (bf16)((acc[rt][ct][r] + bj) * sc);
            }
          }
        }
        __syncthreads();
        const int h = (f0q + p * 64) >> 6;
        const int bh = b * NH + h;
#pragma unroll
        for (int p2 = 0; p2 < 4; ++p2) {
          int slot = p2 * 256 + tid;
          int mr = slot >> 3, cg = slot & 7;
          *(bf16x8*)&outQK[((size_t)bh * SEQ + n0m + mr) * DH + cg * 8] =
              *(const bf16x8*)&sT[mr * 72 + cg * 8];
        }
      }
    } else {
      // V block: bounce through LDS, store V^T coalesced along n
      const int f0 = n0 - 2 * DM;
      const int b = m0 >> 12, n0m = m0 & 4095;
#pragma unroll
      for (int p = 0; p < 2; ++p) {
        __syncthreads();
        if (colbase == p * 64) {
#pragma unroll
          for (int ct = 0; ct < 4; ++ct) {
            int jl = ct * 16 + l15;
            float bj = bias[n0 + p * 64 + jl];
#pragma unroll
            for (int rt = 0; rt < 4; ++rt) {
              int ml = rowbase + rt * 16 + quad * 4;
#pragma unroll
              for (int r = 0; r < 4; ++r)
                sT[jl * 136 + ml + r] = (bf16)(acc[rt][ct][r] + bj);
            }
          }
        }
        __syncthreads();
#pragma unroll
        for (int p2 = 0; p2 < 4; ++p2) {
          int slot = p2 * 256 + tid;
          int jr = slot >> 4, mc = (slot & 15) * 8;
          int fj = f0 + p * 64 + jr;
          int h = fj >> 6, d = fj & 63;
          *(bf16x8*)&outVt[((size_t)(b * NH + h) * DH + d) * SEQ + n0m + mc] =
              *(const bf16x8*)&sT[jr * 136 + mc];
        }
      }
    }
  } else {
#pragma unroll
    for (int ct = 0; ct < 4; ++ct) {
      int j = n0 + colbase + ct * 16 + l15;
      float bj = bias[j];
#pragma unroll
      for (int rt = 0; rt < 4; ++rt) {
        int mrow = m0 + rowbase + rt * 16 + quad * 4;
#pragma unroll
        for (int r = 0; r < 4; ++r)
          outF[(size_t)(mrow + r) * N + j] = acc[rt][ct][r] + bj;
      }
    }
  }
}

// ---------------------------------------------------------------- flash attention v15 (measured best)
// R31 measured: 125.3us, VGPR 80, zero spill, 768 blocks = 3/CU even,
// 32q/wave, single pass. Plateau 123-128 across all structural variants —
// stall-bound at ~33% of dense peak (824 TF effective), at this structure's
// ceiling. Untouched.
__global__ __launch_bounds__(256, 3) void flash_attn(
    const bf16* __restrict__ Q, const bf16* __restrict__ Kg,
    const bf16* __restrict__ Vt, bf16* __restrict__ Oout)
{
  __shared__ bf16 sK[2][64 * 64];    // [key][d], granule-swizzled
  __shared__ bf16 sV[2][64 * 64];    // [d][key], granule-swizzled

  // XCD-aware remap: xcd = L%8 owns heads {X, X+8, X+16}; 32 q-blocks/head.
  const int L    = blockIdx.x + (SEQ / 128) * blockIdx.y;   // 0..767
  const int xcd  = L & 7;
  const int slot = L >> 3;                                  // 0..95
  const int bh   = xcd + 8 * (slot >> 5);                   // 0..23
  const int qb   = slot & 31;

  {
    int ph = (qb + bh) & 3;
    if (ph == 1) __builtin_amdgcn_s_sleep(2);
    else if (ph == 2) __builtin_amdgcn_s_sleep(4);
    else if (ph == 3) __builtin_amdgcn_s_sleep(6);
  }

  const int tid  = threadIdx.x;
  const int wave = tid >> 6;
  const int lane = tid & 63;
  const int l31  = lane & 31;
  const int hi   = lane >> 5;
  const int q0w = qb * 128 + wave * 32;

  const bf16* Qb = Q  + (size_t)bh * SEQ * DH;
  const bf16* Kb = Kg + (size_t)bh * SEQ * DH;
  const bf16* Vb = Vt + (size_t)bh * DH * SEQ;

  const int srow = lane >> 3;
  const int spg  = lane & 7;

  bf16x8 qf[4];
#pragma unroll
  for (int dc = 0; dc < 4; ++dc)
    qf[dc] = *(const bf16x8*)&Qb[(size_t)(q0w + l31) * DH + dc * 16 + hi * 8];

  f32x16 o0 = {}, o1 = {};
  float rs0 = 0.f, rs1 = 0.f, rs2 = 0.f, rs3 = 0.f;   // f32 rowsum accumulators

  const int keyk = (l31 & 7) ^ (((l31 >> 3) & 3) << 1);
  int off[4];                       // shared K/V fragment offsets (identical maps)
#pragma unroll
  for (int dc = 0; dc < 4; ++dc)
    off[dc] = l31 * 64 + (((dc * 2 + hi) ^ keyk) * 8);

  auto stage = [&](int kt, int buf) {
#pragma unroll
    for (int j = 0; j < 2; ++j) {
      int r0 = wave * 16 + j * 8;
      int row = r0 + srow;
      int lg = spg ^ (row & 7) ^ (((row >> 3) & 3) << 1);
      async_ld16(Kb + (size_t)(kt + row) * DH + lg * 8, &sK[buf][r0 * 64]);
      async_ld16(Vb + (size_t)row * SEQ + kt + lg * 8, &sV[buf][r0 * 64]);
    }
  };

  auto compute = [&](const bf16* sKp, const bf16* sVp) {
#pragma unroll
    for (int kb = 0; kb < 2; ++kb) {
      f32x16 s = {};
#pragma unroll
      for (int dc = 0; dc < 4; ++dc) {
        bf16x8 kf = *(const bf16x8*)&sKp[off[dc] + kb * 2048];
        s = __builtin_amdgcn_mfma_f32_32x32x16_bf16(kf, qf[dc], s, 0, 0, 0);
      }
#pragma unroll
      for (int kc = 0; kc < 2; ++kc) {
        int b0 = sexp2_bits(s[8 * kc + 0]);
        int b1 = sexp2_bits(s[8 * kc + 1]);
        int b2 = sexp2_bits(s[8 * kc + 2]);
        int b3 = sexp2_bits(s[8 * kc + 3]);
        int b4 = sexp2_bits(s[8 * kc + 4]);
        int b5 = sexp2_bits(s[8 * kc + 5]);
        int b6 = sexp2_bits(s[8 * kc + 6]);
        int b7 = sexp2_bits(s[8 * kc + 7]);
        // rowsum of the EXACT bf16 P values (hi16 reinterpreted as f32)
        rs0 += __int_as_float(b0 & 0xffff0000) + __int_as_float(b4 & 0xffff0000);
        rs1 += __int_as_float(b1 & 0xffff0000) + __int_as_float(b5 & 0xffff0000);
        rs2 += __int_as_float(b2 & 0xffff0000) + __int_as_float(b6 & 0xffff0000);
        rs3 += __int_as_float(b3 & 0xffff0000) + __int_as_float(b7 & 0xffff0000);
        int g0a = pack_hi16(b0, b1);
        int g0b = pack_hi16(b2, b3);
        int g1a = pack_hi16(b4, b5);
        int g1b = pack_hi16(b6, b7);
        lane32_swap(g0a, g1a);
        lane32_swap(g0b, g1b);
        union { int i[4]; bf16x8 v; } Af;
        Af.i[0] = g0a; Af.i[1] = g0b; Af.i[2] = g1a; Af.i[3] = g1b;
        bf16x8 vf0 = *(const bf16x8*)&sVp[off[kb * 2 + kc]];
        bf16x8 vf1 = *(const bf16x8*)&sVp[off[kb * 2 + kc] + 2048];
        o0 = __builtin_amdgcn_mfma_f32_32x32x16_bf16(Af.v, vf0, o0, 0, 0, 0);
        o1 = __builtin_amdgcn_mfma_f32_32x32x16_bf16(Af.v, vf1, o1, 0, 0, 0);
      }
    }
  };

  stage(0, 0);
  __syncthreads();

  for (int kt = 0; kt < SEQ; kt += 128) {
    if (kt + 64 < SEQ) stage(kt + 64, 1);
    compute(sK[0], sV[0]);
    __syncthreads();
    if (kt + 128 < SEQ) stage(kt + 128, 0);
    compute(sK[1], sV[1]);
    __syncthreads();
  }

  // lane l holds the partial rowsum for q = l&31 over its hi-parity key subset;
  // the complementary subset lives on lane l^32.
  float rsum = (rs0 + rs1) + (rs2 + rs3);
  rsum += __shfl_xor(rsum, 32, 64);
  float invq = 1.0f / rsum;          // lane l: 1/sum for q-row (l&31)

  const int bg = bh / NH, h = bh % NH;
#pragma unroll
  for (int i = 0; i < 16; ++i) {
    int ql = 8 * (i >> 2) + (i & 3) + 4 * hi;
    float inv = __shfl(invq, ql, 64);          // bpermute from lane ql
    size_t base = (size_t)(bg * SEQ + q0w + ql) * DM + h * DH;
    Oout[base + l31]      = (bf16)(o0[i] * inv);
    Oout[base + 32 + l31] = (bf16)(o1[i] * inv);
  }
}

// ---------------------------------------------------------------- launcher
extern "C" void kernel_launch(void* const* d_in, const int* in_sizes, int n_in,
                              void* d_out, int out_size, void* d_ws, size_t ws_size,
                              hipStream_t stream) {
  const float* x     = (const float*)d_in[0];
  const float* qkv_w = (const float*)d_in[1];
  const float* qkv_b = (const float*)d_in[2];
  const float* out_w = (const float*)d_in[3];
  const float* out_b = (const float*)d_in[4];
  float* out = (float*)d_out;

  char* w = (char*)d_ws;
  bf16* xb    = (bf16*)w; w += (size_t)MT * DM * 2;
  bf16* wqkv  = (bf16*)w; w += (size_t)QKVN * DM * 2;
  bf16* wout  = (bf16*)w; w += (size_t)DM * DM * 2;
  bf16* Qw    = (bf16*)w; w += (size_t)MT * DM * 2;        // [bh][n][d], scaled 0.125*log2e
  bf16* Kw    = (bf16*)w; w += (size_t)MT * DM * 2;        // [bh][n][d]
  bf16* Vtw   = (bf16*)w; w += (size_t)MT * DM * 2;        // [bh][d][n]
  bf16* attnV = (bf16*)w; w += (size_t)MT * DM * 2;        // [m][768]

  const int tot4 = NX4 + NW14 + NW24;
  cvt_all<<<dim3((tot4 + 255) / 256), 256, 0, stream>>>(x, qkv_w, out_w, xb, wqkv, wout);

  gemm_bt<0><<<dim3((QKVN / 128) * (MT / 128)), 256, 0, stream>>>(
      xb, wqkv, qkv_b, Qw, Kw, Vtw, nullptr, MT, QKVN, DM);

  flash_attn<<<dim3(SEQ / 128, 2 * NH), 256, 0, stream>>>(Qw, Kw, Vtw, attnV);

  gemm_bt<1><<<dim3((DM / 128) * (MT / 128)), 256, 0, stream>>>(
      attnV, wout, out_b, nullptr, nullptr, nullptr, out, MT, DM, DM);
}